// Round 3
// baseline (1049.497 us; speedup 1.0000x reference)
//
#include <hip/hip_runtime.h>
#include <hip/hip_bf16.h>
#include <hip/hip_fp16.h>

typedef __hip_bfloat16 bf16;

#define EPS 1e-5f
#define NSLOPE 0.01f

__device__ __forceinline__ float b2f(bf16 v) { return __bfloat162float(v); }

// dtype-flexible scalar load: element idx of a logical float array
__device__ __forceinline__ float ld1(const void* p, size_t idx, int isbf) {
  if (isbf) return b2f(((const bf16*)p)[idx]);
  return ((const float*)p)[idx];
}
// dtype-flexible scalar store
__device__ __forceinline__ void st1(void* p, size_t idx, int isbf, float v) {
  if (isbf) ((bf16*)p)[idx] = __float2bfloat16(v);
  else      ((float*)p)[idx] = v;
}
// convert 8 packed bf16 (uint4) -> 8 floats (exact)
__device__ __forceinline__ void bf8_to_f8(uint4 u, float* dst) {
  unsigned w[4] = {u.x, u.y, u.z, u.w};
#pragma unroll
  for (int k = 0; k < 4; ++k) {
    dst[2 * k]     = __uint_as_float(w[k] << 16);
    dst[2 * k + 1] = __uint_as_float(w[k] & 0xffff0000u);
  }
}

// ---------------------------------------------------------------------------
// K0: meta (row_start, len per batch) + input-dtype sniffer.
// Sniffer: for packed bf16, the LOW half of every 32b word is a sane-exponent
// bf16; for float32 it's mantissa noise. Ballot over 64 words decides.
// ---------------------------------------------------------------------------
__global__ void meta_kernel(const void* __restrict__ xt,
                            const int* __restrict__ bidx, const int* __restrict__ pidx,
                            int N, int B, int* __restrict__ rs, int* __restrict__ ln,
                            int* __restrict__ flag) {
  if (threadIdx.x < 64) {
    unsigned w = ((const unsigned*)xt)[threadIdx.x];
    unsigned lo = w & 0xffffu;
    unsigned ex = (lo >> 7) & 0xffu;
    bool sane = ((lo & 0x7fffu) == 0u) || (ex >= 96u && ex <= 134u);
    unsigned long long m = __ballot(sane);
    if (threadIdx.x == 0) flag[0] = (__popcll(m) >= 48) ? 1 : 0;
  }
  for (int i = threadIdx.x; i < N; i += blockDim.x) {
    int b = bidx[i];
    if ((unsigned)b >= (unsigned)B) continue;
    if (i == 0 || bidx[i - 1] != b) rs[b] = i;
    if (i == N - 1 || bidx[i + 1] != b) ln[b] = pidx[i] + 1;
  }
}

// ---------------------------------------------------------------------------
// Kf: flag-aware zero fill of x_out (fallback when ws too small)
// ---------------------------------------------------------------------------
__global__ void zfill_kernel(void* out, const int* __restrict__ flag, long long n) {
  const int isbf = flag[0];
  long long i = (long long)blockIdx.x * blockDim.x + threadIdx.x;
  long long stride = (long long)gridDim.x * blockDim.x;
  for (; i < n; i += stride) st1(out, (size_t)i, isbf, 0.f);
}

// ---------------------------------------------------------------------------
// K1: h[n][o] = leaky(bn1(concat(x_temp[n], x_stat[batch_idx[n]]) @ W1^T + b1))
// 16 rows/block; W1 staged LDS-transposed. h stored bf16 in workspace.
// ---------------------------------------------------------------------------
__global__ __launch_bounds__(256) void h_kernel(
    const void* __restrict__ xt, const void* __restrict__ xsg,
    const int* __restrict__ bidx,
    const void* __restrict__ W1, const void* __restrict__ b1,
    const void* __restrict__ g1, const void* __restrict__ be1,
    const void* __restrict__ mn1, const void* __restrict__ vr1,
    const int* __restrict__ flag, bf16* __restrict__ hout, int N) {
  __shared__ bf16 w1t[192 * 128];     // [i][o]
  __shared__ float xs[16][192];
  const int isbf = flag[0];
  const int tid = threadIdx.x;
  for (int e = tid; e < 24576; e += 256) {
    int o = e / 192, i = e - o * 192;
    w1t[i * 128 + o] = __float2bfloat16(ld1(W1, e, isbf));
  }
  const int base = blockIdx.x * 16;
  for (int e = tid; e < 3072; e += 256) {
    int r = e / 192, i = e - r * 192;
    int n = base + r;
    float v = 0.f;
    if (n < N) {
      if (i < 128) v = ld1(xt, (size_t)n * 128 + i, isbf);
      else         v = ld1(xsg, (size_t)bidx[n] * 64 + (i - 128), isbf);
    }
    xs[r][i] = v;
  }
  __syncthreads();

  const int op = (tid & 63) * 2;   // output pair
  const int rq = tid >> 6;         // rows rq, rq+4, rq+8, rq+12
  float acc[4][2] = {{0.f,0.f},{0.f,0.f},{0.f,0.f},{0.f,0.f}};
  for (int i = 0; i < 192; ++i) {
    float w0 = b2f(w1t[i * 128 + op]);
    float w1 = b2f(w1t[i * 128 + op + 1]);
#pragma unroll
    for (int k = 0; k < 4; ++k) {
      float x = xs[rq + 4 * k][i];
      acc[k][0] += x * w0;
      acc[k][1] += x * w1;
    }
  }
#pragma unroll
  for (int u = 0; u < 2; ++u) {
    int o = op + u;
    float k1 = ld1(g1, o, isbf) * rsqrtf(ld1(vr1, o, isbf) + EPS);
    float k0 = ld1(be1, o, isbf) - ld1(mn1, o, isbf) * k1;
    float bias = ld1(b1, o, isbf);
#pragma unroll
    for (int k = 0; k < 4; ++k) {
      int n = base + rq + 4 * k;
      if (n < N) {
        float v = (acc[k][u] + bias) * k1 + k0;
        v = (v >= 0.f) ? v : NSLOPE * v;
        hout[(size_t)n * 128 + o] = __float2bfloat16(v);
      }
    }
  }
}

// ---------------------------------------------------------------------------
// K2: x_stat_out = leaky(bn2(x_stat @ W2^T + b2)) -> d_out[N*128 + b*64 + o]
// ---------------------------------------------------------------------------
__global__ __launch_bounds__(64) void stat_kernel(
    const void* __restrict__ xstat, const void* __restrict__ W2,
    const void* __restrict__ b2, const void* __restrict__ g2,
    const void* __restrict__ be2, const void* __restrict__ mn2,
    const void* __restrict__ vr2, const int* __restrict__ flag,
    void* __restrict__ out, long long obase) {
  __shared__ float xs[64];
  const int isbf = flag[0];
  const int b = blockIdx.x, o = threadIdx.x;
  xs[o] = ld1(xstat, b * 64 + o, isbf);
  __syncthreads();
  float acc = ld1(b2, o, isbf);
#pragma unroll 8
  for (int j = 0; j < 64; ++j) acc += xs[j] * ld1(W2, o * 64 + j, isbf);
  float k1 = ld1(g2, o, isbf) * rsqrtf(ld1(vr2, o, isbf) + EPS);
  float k0 = ld1(be2, o, isbf) - ld1(mn2, o, isbf) * k1;
  float v = acc * k1 + k0;
  v = (v >= 0.f) ? v : NSLOPE * v;
  st1(out, (size_t)(obase + b * 64 + o), isbf, v);
}

// ---------------------------------------------------------------------------
// K3: fused attention. One block = 16 query rows of one batch.
// h is bf16 in workspace (internal format, dtype-independent).
// ---------------------------------------------------------------------------
__global__ __launch_bounds__(256) void attn_kernel(
    const void* __restrict__ ta, const bf16* __restrict__ h,
    const int* __restrict__ rs_arr, const int* __restrict__ ln_arr,
    const int* __restrict__ flag, void* __restrict__ xout, int T) {
  __shared__ float q[16][132];        // +4 pad
  __shared__ float kv[32][132];
  __shared__ __half sc[16][1024];     // qk logits, then weights (T <= 1024)

  const int b = blockIdx.y;
  const int t0 = blockIdx.x * 16;
  const int len = ln_arr[b];
  if (t0 >= len) return;              // uniform early-exit
  const int isbf = flag[0];
  const int rs = rs_arr[b];
  const int nrows = min(16, len - t0);
  const int tid = threadIdx.x;

  // stage Q
  {
    int r = tid >> 4, c8 = (tid & 15) << 3;
    float v8[8] = {0,0,0,0,0,0,0,0};
    if (r < nrows) {
      uint4 u = *(const uint4*)(h + (size_t)(rs + t0 + r) * 128 + c8);
      bf8_to_f8(u, v8);
    }
    *(float4*)&q[r][c8]     = *(float4*)&v8[0];
    *(float4*)&q[r][c8 + 4] = *(float4*)&v8[4];
  }

  const float scale = 0.08838834764831845f;  // 1/sqrt(128)

  // -------- phase 1: qk --------
  const int r1 = tid & 15, sg = tid >> 4;
  for (int s0 = 0; s0 < len; s0 += 32) {
    __syncthreads();
    for (int e = tid; e < 512; e += 256) {       // 32 rows x 16 chunks
      int sj = e >> 4, c8 = (e & 15) << 3;
      int s = s0 + sj;
      float v8[8] = {0,0,0,0,0,0,0,0};
      if (s < len) {
        uint4 u = *(const uint4*)(h + (size_t)(rs + s) * 128 + c8);
        bf8_to_f8(u, v8);
      }
      *(float4*)&kv[sj][c8]     = *(float4*)&v8[0];
      *(float4*)&kv[sj][c8 + 4] = *(float4*)&v8[4];
    }
    __syncthreads();
    const int sl = sg << 1;
    float a0 = 0.f, a1 = 0.f;
#pragma unroll 8
    for (int c = 0; c < 128; c += 4) {
      float4 qv = *(const float4*)&q[r1][c];
      float4 k0 = *(const float4*)&kv[sl][c];
      float4 k1 = *(const float4*)&kv[sl + 1][c];
      a0 += qv.x * k0.x + qv.y * k0.y + qv.z * k0.z + qv.w * k0.w;
      a1 += qv.x * k1.x + qv.y * k1.y + qv.z * k1.z + qv.w * k1.w;
    }
    int s = s0 + sl;
    if (s < len)     sc[r1][s]     = __float2half(a0 * scale);
    if (s + 1 < len) sc[r1][s + 1] = __float2half(a1 * scale);
  }
  __syncthreads();

  // -------- phase 2: softmax (+ analytic zero-padding term) + temp_attn ----
  const int wv = tid >> 6, lane = tid & 63;
  for (int j = 0; j < 4; ++j) {
    int r = wv + (j << 2);
    if (r >= nrows) continue;   // no barriers in this phase
    float m = -INFINITY;
    for (int s = lane; s < len; s += 64) m = fmaxf(m, __half2float(sc[r][s]));
#pragma unroll
    for (int off = 32; off >= 1; off >>= 1) m = fmaxf(m, __shfl_xor(m, off, 64));
    if (len < T) m = fmaxf(m, 0.f);   // padded zero logits join the max
    float l = 0.f;
    for (int s = lane; s < len; s += 64) l += __expf(__half2float(sc[r][s]) - m);
#pragma unroll
    for (int off = 32; off >= 1; off >>= 1) l += __shfl_xor(l, off, 64);
    float Z = l + (float)(T - len) * __expf(-m);
    float inv = 1.f / Z;
    size_t tabase = ((size_t)b * T + (t0 + r)) * T;
    for (int s = lane; s < len; s += 64) {
      float w = __expf(__half2float(sc[r][s]) - m) * inv + ld1(ta, tabase + s, isbf);
      sc[r][s] = __float2half(w);
    }
  }

  // -------- phase 3: out = w @ V --------
  const int r3 = tid >> 4, c0 = (tid & 15) << 3;
  float acc[8] = {0.f, 0.f, 0.f, 0.f, 0.f, 0.f, 0.f, 0.f};
  for (int s0 = 0; s0 < len; s0 += 32) {
    __syncthreads();   // orders phase2 sc writes; protects kv reuse
    for (int e = tid; e < 512; e += 256) {
      int sj = e >> 4, c8 = (e & 15) << 3;
      int s = s0 + sj;
      float v8[8] = {0,0,0,0,0,0,0,0};
      if (s < len) {
        uint4 u = *(const uint4*)(h + (size_t)(rs + s) * 128 + c8);
        bf8_to_f8(u, v8);
      }
      *(float4*)&kv[sj][c8]     = *(float4*)&v8[0];
      *(float4*)&kv[sj][c8 + 4] = *(float4*)&v8[4];
    }
    __syncthreads();
    const int smax = min(32, len - s0);
    for (int sj = 0; sj < smax; ++sj) {
      float w = __half2float(sc[r3][s0 + sj]);
      float4 va = *(const float4*)&kv[sj][c0];
      float4 vb = *(const float4*)&kv[sj][c0 + 4];
      acc[0] += w * va.x; acc[1] += w * va.y; acc[2] += w * va.z; acc[3] += w * va.w;
      acc[4] += w * vb.x; acc[5] += w * vb.y; acc[6] += w * vb.z; acc[7] += w * vb.w;
    }
  }
  if (r3 < nrows) {
    size_t ob = (size_t)(rs + t0 + r3) * 128 + c0;
#pragma unroll
    for (int j = 0; j < 8; ++j) st1(xout, ob + j, isbf, acc[j]);
  }
}

// ---------------------------------------------------------------------------
extern "C" void kernel_launch(void* const* d_in, const int* in_sizes, int n_in,
                              void* d_out, int out_size, void* d_ws, size_t ws_size,
                              hipStream_t stream) {
  const void* x_temp    = d_in[0];
  const void* x_stat    = d_in[1];
  const void* temp_attn = d_in[2];
  const int N = in_sizes[0] / 128;      // 23450
  const int B = in_sizes[1] / 64;       // 32
  long long tt = (long long)in_sizes[2] / B;
  int T = 1; while ((long long)(T + 1) * (T + 1) <= tt) ++T;  // isqrt -> 1024

  // scan for batch_idx: first entry after temp_attn with exactly N elements
  int p = 3;
  while (p < n_in && in_sizes[p] != N) ++p;
  const int* batch_idx = (const int*)d_in[p++];      // size N
  const int* pos_idx   = (const int*)d_in[p++];      // size N
  const void* W1 = d_in[p++];                        // 128*192
  const void* b1 = d_in[p++];
  const void* g1 = d_in[p++];
  const void* be1= d_in[p++];
  const void* mn1= d_in[p++];
  const void* vr1= d_in[p++];
  const void* W2 = d_in[p++];                        // 64*64
  const void* b2 = d_in[p++];
  const void* g2 = d_in[p++];
  const void* be2= d_in[p++];
  const void* mn2= d_in[p++];
  const void* vr2= d_in[p++];

  int*  meta = (int*)d_ws;           // rs[B] | ln[B] | flag
  int*  rs   = meta;
  int*  lnp  = meta + B;
  int*  flag = meta + 2 * B;
  bf16* h    = (bf16*)((char*)d_ws + 1024);          // N x 128 bf16
  size_t need = 1024 + (size_t)N * 128 * sizeof(bf16);

  long long obase = (long long)N * 128;

  meta_kernel<<<1, 256, 0, stream>>>(x_temp, batch_idx, pos_idx, N, B, rs, lnp, flag);
  stat_kernel<<<B, 64, 0, stream>>>(x_stat, W2, b2, g2, be2, mn2, vr2, flag,
                                    d_out, obase);
  if (ws_size >= need) {
    h_kernel<<<(N + 15) / 16, 256, 0, stream>>>(x_temp, x_stat, batch_idx,
                                                W1, b1, g1, be1, mn1, vr1, flag, h, N);
    attn_kernel<<<dim3((T + 15) / 16, B), 256, 0, stream>>>(temp_attn, h, rs, lnp,
                                                            flag, d_out, T);
  } else {
    // diagnostic fallback: x_out <- 0 (signature: absmax == max|ref| ~ 25.25)
    zfill_kernel<<<512, 256, 0, stream>>>(d_out, flag, obase);
  }
}

// Round 4
// 611.895 us; speedup vs baseline: 1.7152x; 1.7152x over previous
//
#include <hip/hip_runtime.h>
#include <hip/hip_bf16.h>
#include <hip/hip_fp16.h>

typedef __hip_bfloat16 bf16;
typedef __attribute__((ext_vector_type(8))) short short8;
typedef __attribute__((ext_vector_type(4))) float f32x4;

#define EPS 1e-5f
#define NSLOPE 0.01f

__device__ __forceinline__ float b2f(bf16 v) { return __bfloat162float(v); }

__device__ __forceinline__ float ld1(const void* p, size_t idx, int isbf) {
  if (isbf) return b2f(((const bf16*)p)[idx]);
  return ((const float*)p)[idx];
}
__device__ __forceinline__ void st1(void* p, size_t idx, int isbf, float v) {
  if (isbf) ((bf16*)p)[idx] = __float2bfloat16(v);
  else      ((float*)p)[idx] = v;
}

// ---------------------------------------------------------------------------
// K0: meta (row_start, len per batch) + input-dtype sniffer (block 0 only).
// ---------------------------------------------------------------------------
__global__ void meta_kernel(const void* __restrict__ xt,
                            const int* __restrict__ bidx, const int* __restrict__ pidx,
                            int N, int B, int* __restrict__ rs, int* __restrict__ ln,
                            int* __restrict__ flag) {
  if (blockIdx.x == 0 && threadIdx.x < 64) {
    unsigned w = ((const unsigned*)xt)[threadIdx.x];
    unsigned lo = w & 0xffffu;
    unsigned ex = (lo >> 7) & 0xffu;
    bool sane = ((lo & 0x7fffu) == 0u) || (ex >= 96u && ex <= 134u);
    unsigned long long m = __ballot(sane);
    if (threadIdx.x == 0) flag[0] = (__popcll(m) >= 48) ? 1 : 0;
  }
  int stride = gridDim.x * blockDim.x;
  for (int i = blockIdx.x * blockDim.x + threadIdx.x; i < N; i += stride) {
    int b = bidx[i];
    if ((unsigned)b >= (unsigned)B) continue;
    if (i == 0 || bidx[i - 1] != b) rs[b] = i;
    if (i == N - 1 || bidx[i + 1] != b) ln[b] = pidx[i] + 1;
  }
}

// ---------------------------------------------------------------------------
// Kf: flag-aware zero fill of x_out (fallback when ws too small)
// ---------------------------------------------------------------------------
__global__ void zfill_kernel(void* out, const int* __restrict__ flag, long long n) {
  const int isbf = flag[0];
  long long i = (long long)blockIdx.x * blockDim.x + threadIdx.x;
  long long stride = (long long)gridDim.x * blockDim.x;
  for (; i < n; i += stride) st1(out, (size_t)i, isbf, 0.f);
}

// ---------------------------------------------------------------------------
// K1: h[n][o] = leaky(bn1(concat(x_temp[n], x_stat[batch_idx[n]]) @ W1^T + b1))
// (unchanged from round 3 — passed; revisit if it surfaces in top-5)
// ---------------------------------------------------------------------------
__global__ __launch_bounds__(256) void h_kernel(
    const void* __restrict__ xt, const void* __restrict__ xsg,
    const int* __restrict__ bidx,
    const void* __restrict__ W1, const void* __restrict__ b1,
    const void* __restrict__ g1, const void* __restrict__ be1,
    const void* __restrict__ mn1, const void* __restrict__ vr1,
    const int* __restrict__ flag, bf16* __restrict__ hout, int N) {
  __shared__ bf16 w1t[192 * 128];     // [i][o]
  __shared__ float xs[16][192];
  const int isbf = flag[0];
  const int tid = threadIdx.x;
  for (int e = tid; e < 24576; e += 256) {
    int o = e / 192, i = e - o * 192;
    w1t[i * 128 + o] = __float2bfloat16(ld1(W1, e, isbf));
  }
  const int base = blockIdx.x * 16;
  for (int e = tid; e < 3072; e += 256) {
    int r = e / 192, i = e - r * 192;
    int n = base + r;
    float v = 0.f;
    if (n < N) {
      if (i < 128) v = ld1(xt, (size_t)n * 128 + i, isbf);
      else         v = ld1(xsg, (size_t)bidx[n] * 64 + (i - 128), isbf);
    }
    xs[r][i] = v;
  }
  __syncthreads();

  const int op = (tid & 63) * 2;
  const int rq = tid >> 6;
  float acc[4][2] = {{0.f,0.f},{0.f,0.f},{0.f,0.f},{0.f,0.f}};
  for (int i = 0; i < 192; ++i) {
    float w0 = b2f(w1t[i * 128 + op]);
    float w1 = b2f(w1t[i * 128 + op + 1]);
#pragma unroll
    for (int k = 0; k < 4; ++k) {
      float x = xs[rq + 4 * k][i];
      acc[k][0] += x * w0;
      acc[k][1] += x * w1;
    }
  }
#pragma unroll
  for (int u = 0; u < 2; ++u) {
    int o = op + u;
    float k1 = ld1(g1, o, isbf) * rsqrtf(ld1(vr1, o, isbf) + EPS);
    float k0 = ld1(be1, o, isbf) - ld1(mn1, o, isbf) * k1;
    float bias = ld1(b1, o, isbf);
#pragma unroll
    for (int k = 0; k < 4; ++k) {
      int n = base + rq + 4 * k;
      if (n < N) {
        float v = (acc[k][u] + bias) * k1 + k0;
        v = (v >= 0.f) ? v : NSLOPE * v;
        hout[(size_t)n * 128 + o] = __float2bfloat16(v);
      }
    }
  }
}

// ---------------------------------------------------------------------------
// K2: x_stat_out = leaky(bn2(x_stat @ W2^T + b2))
// ---------------------------------------------------------------------------
__global__ __launch_bounds__(64) void stat_kernel(
    const void* __restrict__ xstat, const void* __restrict__ W2,
    const void* __restrict__ b2, const void* __restrict__ g2,
    const void* __restrict__ be2, const void* __restrict__ mn2,
    const void* __restrict__ vr2, const int* __restrict__ flag,
    void* __restrict__ out, long long obase) {
  __shared__ float xs[64];
  const int isbf = flag[0];
  const int b = blockIdx.x, o = threadIdx.x;
  xs[o] = ld1(xstat, b * 64 + o, isbf);
  __syncthreads();
  float acc = ld1(b2, o, isbf);
#pragma unroll 8
  for (int j = 0; j < 64; ++j) acc += xs[j] * ld1(W2, o * 64 + j, isbf);
  float k1 = ld1(g2, o, isbf) * rsqrtf(ld1(vr2, o, isbf) + EPS);
  float k0 = ld1(be2, o, isbf) - ld1(mn2, o, isbf) * k1;
  float v = acc * k1 + k0;
  v = (v >= 0.f) ? v : NSLOPE * v;
  st1(out, (size_t)(obase + b * 64 + o), isbf, v);
}

// ---------------------------------------------------------------------------
// K3: MFMA attention. One block = 16 query rows of one batch, 4 waves.
// Phase 1: S = QK^T via mfma_16x16x32_bf16, Q/K frags direct from global h.
//          Logits (fp16) -> Ss. Padded s (>=len) get exact 0 logits.
// Phase 2: softmax over all T (pad zeros included naturally) + temp_attn,
//          P written back to Ss as bf16 (A-operand for PV).
// Phase 3: O = P V via MFMA; V chunks (64 x 128) staged transposed in vT.
//          P tail (s>=len) annihilated by zeroed V rows.
// ---------------------------------------------------------------------------
__global__ __launch_bounds__(256) void attn_mfma_kernel(
    const void* __restrict__ ta, const bf16* __restrict__ h,
    const int* __restrict__ rs_arr, const int* __restrict__ ln_arr,
    const int* __restrict__ flag, void* __restrict__ xout, int T, int N) {
  // Ss rows: 1032 halves (pad 8) -> row stride 516 dwords (= 4 mod 32, 16B-aligned)
  __shared__ __align__(16) unsigned short Ss[16][1032];
  // vT rows: 66 halves -> 33 dwords (odd: spreads banks), b32-aligned even cols
  __shared__ __align__(16) unsigned short vT[128][66];

  const int b = blockIdx.y, t0 = blockIdx.x * 16;
  const int len = ln_arr[b];
  if (t0 >= len) return;              // uniform exit before any barrier
  const int isbf = flag[0];
  const int rs = rs_arr[b];
  const int nrows = min(16, len - t0);
  const int tid = threadIdx.x;
  const int lane = tid & 63, wv = tid >> 6;
  const int m16 = lane & 15, quad = lane >> 4;

  // ---- Q fragments (A operand): A[m][k], m=lane&15, k=quad*8+j ----
  short8 qf[4];
  {
    int qrow = rs + t0 + m16;
    if (qrow > N - 1) qrow = N - 1;   // clamp: value unused for t>=len rows
    const bf16* qp = h + (size_t)qrow * 128 + quad * 8;
#pragma unroll
    for (int ks = 0; ks < 4; ++ks)
      qf[ks] = *(const short8*)(qp + ks * 32);
  }

  const float scale = 0.08838834764831845f;   // 1/sqrt(128)
  const int ntiles = (T + 15) >> 4;

  // -------- phase 1: logits --------
  for (int st = wv; st < ntiles; st += 4) {
    int s = st * 16 + m16;
    if (st * 16 >= len) {             // all-pad tile: zero logits, skip MFMA
      if (s < T) {
#pragma unroll
        for (int r = 0; r < 4; ++r) Ss[quad * 4 + r][s] = 0;
      }
      continue;
    }
    f32x4 acc = {0.f, 0.f, 0.f, 0.f};
    const bf16* kp = h + (size_t)(rs + s) * 128 + quad * 8;
    const bool v = (s < len);
#pragma unroll
    for (int ks = 0; ks < 4; ++ks) {
      short8 kf = {0, 0, 0, 0, 0, 0, 0, 0};
      if (v) kf = *(const short8*)(kp + ks * 32);
      acc = __builtin_amdgcn_mfma_f32_16x16x32_bf16(qf[ks], kf, acc, 0, 0, 0);
    }
    // D: col = lane&15 (= s), row = quad*4 + r (= t)
    if (s < T) {
#pragma unroll
      for (int r = 0; r < 4; ++r)
        Ss[quad * 4 + r][s] = __half_as_ushort(__float2half(acc[r] * scale));
    }
  }
  __syncthreads();

  // -------- phase 2: softmax + temp_attn; write P as bf16 --------
  {
    const int Tpad = (T + 63) & ~63;          // PV A-frags read up to here
    for (int j = 0; j < 4; ++j) {
      int r = wv + (j << 2);                  // all 16 rows (t0+r < T always)
      float vals[16];
      int nv = 0;
      for (int s = lane; s < T && nv < 16; s += 64)
        vals[nv++] = __half2float(__ushort_as_half(Ss[r][s]));
      float mx = -INFINITY;
      for (int k = 0; k < nv; ++k) mx = fmaxf(mx, vals[k]);
#pragma unroll
      for (int off = 32; off >= 1; off >>= 1) mx = fmaxf(mx, __shfl_xor(mx, off, 64));
      float l = 0.f;
      for (int k = 0; k < nv; ++k) { vals[k] = __expf(vals[k] - mx); l += vals[k]; }
#pragma unroll
      for (int off = 32; off >= 1; off >>= 1) l += __shfl_xor(l, off, 64);
      float inv = 1.f / l;
      size_t tabase = ((size_t)b * T + (t0 + r)) * (size_t)T;
      int k = 0;
      for (int s = lane; s < Tpad; s += 64) {
        float p = 0.f;
        if (s < T) { p = vals[k++] * inv + ld1(ta, tabase + s, isbf); }
        *(bf16*)&Ss[r][s] = __float2bfloat16(p);
      }
    }
  }
  __syncthreads();

  // -------- phase 3: O = P V --------
  f32x4 oacc0 = {0.f, 0.f, 0.f, 0.f};
  f32x4 oacc1 = {0.f, 0.f, 0.f, 0.f};
  for (int s0 = 0; s0 < len; s0 += 64) {
    // stage vT: rows c (128), cols s-s0 (64); zero for s >= len
    for (int e = tid; e < 512; e += 256) {
      int sp = e >> 4, c8 = (e & 15) << 3;
      int s = s0 + 2 * sp;
      uint4 u0 = {0, 0, 0, 0}, u1 = {0, 0, 0, 0};
      if (s < len)     u0 = *(const uint4*)(h + (size_t)(rs + s) * 128 + c8);
      if (s + 1 < len) u1 = *(const uint4*)(h + (size_t)(rs + s + 1) * 128 + c8);
      const unsigned short* a0 = (const unsigned short*)&u0;
      const unsigned short* a1 = (const unsigned short*)&u1;
#pragma unroll
      for (int j = 0; j < 8; ++j)
        *(unsigned*)&vT[c8 + j][2 * sp] = (unsigned)a0[j] | ((unsigned)a1[j] << 16);
    }
    __syncthreads();
#pragma unroll
    for (int ks = 0; ks < 2; ++ks) {
      // A-frag: P[m16][s0 + ks*32 + quad*8 + j]  (b128, 2-way-free banks)
      short8 af = *(const short8*)&Ss[m16][s0 + ks * 32 + quad * 8];
#pragma unroll
      for (int ct = 0; ct < 2; ++ct) {
        const int c0 = wv * 32 + ct * 16;
        // B-frag: V[s0+k][c0+n] = vT[c0+m16][k], k = ks*32 + quad*8 + j
        const unsigned short* vrow = &vT[c0 + m16][ks * 32 + quad * 8];
        unsigned w0 = *(const unsigned*)(vrow + 0);
        unsigned w1 = *(const unsigned*)(vrow + 2);
        unsigned w2 = *(const unsigned*)(vrow + 4);
        unsigned w3 = *(const unsigned*)(vrow + 6);
        short8 bfv;
        bfv[0] = (short)(w0 & 0xffffu); bfv[1] = (short)(w0 >> 16);
        bfv[2] = (short)(w1 & 0xffffu); bfv[3] = (short)(w1 >> 16);
        bfv[4] = (short)(w2 & 0xffffu); bfv[5] = (short)(w2 >> 16);
        bfv[6] = (short)(w3 & 0xffffu); bfv[7] = (short)(w3 >> 16);
        if (ct == 0)
          oacc0 = __builtin_amdgcn_mfma_f32_16x16x32_bf16(af, bfv, oacc0, 0, 0, 0);
        else
          oacc1 = __builtin_amdgcn_mfma_f32_16x16x32_bf16(af, bfv, oacc1, 0, 0, 0);
      }
    }
    __syncthreads();   // protect vT before next restage
  }

  // epilogue: D col = lane&15 (= output col), row = quad*4 + r (= t)
#pragma unroll
  for (int r = 0; r < 4; ++r) {
    int t = quad * 4 + r;
    if (t < nrows) {
      size_t ob = (size_t)(rs + t0 + t) * 128;
      st1(xout, ob + wv * 32 + m16,      isbf, oacc0[r]);
      st1(xout, ob + wv * 32 + 16 + m16, isbf, oacc1[r]);
    }
  }
}

// ---------------------------------------------------------------------------
extern "C" void kernel_launch(void* const* d_in, const int* in_sizes, int n_in,
                              void* d_out, int out_size, void* d_ws, size_t ws_size,
                              hipStream_t stream) {
  const void* x_temp    = d_in[0];
  const void* x_stat    = d_in[1];
  const void* temp_attn = d_in[2];
  const int N = in_sizes[0] / 128;      // 23450
  const int B = in_sizes[1] / 64;       // 32
  long long tt = (long long)in_sizes[2] / B;
  int T = 1; while ((long long)(T + 1) * (T + 1) <= tt) ++T;  // isqrt -> 1024

  int p = 3;
  while (p < n_in && in_sizes[p] != N) ++p;
  const int* batch_idx = (const int*)d_in[p++];
  const int* pos_idx   = (const int*)d_in[p++];
  const void* W1 = d_in[p++];
  const void* b1 = d_in[p++];
  const void* g1 = d_in[p++];
  const void* be1= d_in[p++];
  const void* mn1= d_in[p++];
  const void* vr1= d_in[p++];
  const void* W2 = d_in[p++];
  const void* b2 = d_in[p++];
  const void* g2 = d_in[p++];
  const void* be2= d_in[p++];
  const void* mn2= d_in[p++];
  const void* vr2= d_in[p++];

  int*  meta = (int*)d_ws;
  int*  rs   = meta;
  int*  lnp  = meta + B;
  int*  flag = meta + 2 * B;
  bf16* h    = (bf16*)((char*)d_ws + 1024);
  size_t need = 1024 + (size_t)N * 128 * sizeof(bf16);

  long long obase = (long long)N * 128;

  meta_kernel<<<90, 256, 0, stream>>>(x_temp, batch_idx, pos_idx, N, B, rs, lnp, flag);
  stat_kernel<<<B, 64, 0, stream>>>(x_stat, W2, b2, g2, be2, mn2, vr2, flag,
                                    d_out, obase);
  if (ws_size >= need) {
    h_kernel<<<(N + 15) / 16, 256, 0, stream>>>(x_temp, x_stat, batch_idx,
                                                W1, b1, g1, be1, mn1, vr1, flag, h, N);
    attn_mfma_kernel<<<dim3((T + 15) / 16, B), 256, 0, stream>>>(
        temp_attn, h, rs, lnp, flag, d_out, T, N);
  } else {
    zfill_kernel<<<512, 256, 0, stream>>>(d_out, flag, obase);
  }
}

// Round 5
// 494.680 us; speedup vs baseline: 2.1216x; 1.2370x over previous
//
#include <hip/hip_runtime.h>
#include <hip/hip_bf16.h>
#include <hip/hip_fp16.h>

typedef __hip_bfloat16 bf16;
typedef __attribute__((ext_vector_type(8))) short short8;
typedef __attribute__((ext_vector_type(4))) float f32x4;

#define EPS 1e-5f
#define NSLOPE 0.01f

__device__ __forceinline__ float b2f(bf16 v) { return __bfloat162float(v); }

__device__ __forceinline__ float ld1(const void* p, size_t idx, int isbf) {
  if (isbf) return b2f(((const bf16*)p)[idx]);
  return ((const float*)p)[idx];
}
__device__ __forceinline__ void st1(void* p, size_t idx, int isbf, float v) {
  if (isbf) ((bf16*)p)[idx] = __float2bfloat16(v);
  else      ((float*)p)[idx] = v;
}
__device__ __forceinline__ short f2bs(float x) {
  bf16 t = __float2bfloat16(x);
  short s; __builtin_memcpy(&s, &t, 2); return s;
}
// pack 8 consecutive floats -> short8 of bf16
__device__ __forceinline__ short8 pack8f(const float* p) {
  float4 a = *(const float4*)p, b = *(const float4*)(p + 4);
  short8 r;
  r[0] = f2bs(a.x); r[1] = f2bs(a.y); r[2] = f2bs(a.z); r[3] = f2bs(a.w);
  r[4] = f2bs(b.x); r[5] = f2bs(b.y); r[6] = f2bs(b.z); r[7] = f2bs(b.w);
  return r;
}

// ---------------------------------------------------------------------------
// K0: meta (row_start, len per batch) + input-dtype sniffer (block 0 only).
// ---------------------------------------------------------------------------
__global__ void meta_kernel(const void* __restrict__ xt,
                            const int* __restrict__ bidx, const int* __restrict__ pidx,
                            int N, int B, int* __restrict__ rs, int* __restrict__ ln,
                            int* __restrict__ flag) {
  if (blockIdx.x == 0 && threadIdx.x < 64) {
    unsigned w = ((const unsigned*)xt)[threadIdx.x];
    unsigned lo = w & 0xffffu;
    unsigned ex = (lo >> 7) & 0xffu;
    bool sane = ((lo & 0x7fffu) == 0u) || (ex >= 96u && ex <= 134u);
    unsigned long long m = __ballot(sane);
    if (threadIdx.x == 0) flag[0] = (__popcll(m) >= 48) ? 1 : 0;
  }
  int stride = gridDim.x * blockDim.x;
  for (int i = blockIdx.x * blockDim.x + threadIdx.x; i < N; i += stride) {
    int b = bidx[i];
    if ((unsigned)b >= (unsigned)B) continue;
    if (i == 0 || bidx[i - 1] != b) rs[b] = i;
    if (i == N - 1 || bidx[i + 1] != b) ln[b] = pidx[i] + 1;
  }
}

// ---------------------------------------------------------------------------
// Kf: flag-aware zero fill of x_out (fallback when ws too small)
// ---------------------------------------------------------------------------
__global__ void zfill_kernel(void* out, const int* __restrict__ flag, long long n) {
  const int isbf = flag[0];
  long long i = (long long)blockIdx.x * blockDim.x + threadIdx.x;
  long long stride = (long long)gridDim.x * blockDim.x;
  for (; i < n; i += stride) st1(out, (size_t)i, isbf, 0.f);
}

// ---------------------------------------------------------------------------
// K1: h = leaky(bn1(concat(x_temp, x_stat[bidx]) @ W1^T + b1))  via MFMA.
// Block = 64 rows x 128 cols, 4 waves (1 wave = 16 rows x 128 cols).
// A-frags (x rows) and B-frags (W1 rows) loaded DIRECTLY from global
// (16B-contiguous in k); no LDS, no barriers. 48 MFMAs/wave, K=192.
// ---------------------------------------------------------------------------
__global__ __launch_bounds__(256) void h_mfma_kernel(
    const void* __restrict__ xt, const void* __restrict__ xsg,
    const int* __restrict__ bidx,
    const void* __restrict__ W1, const void* __restrict__ b1,
    const void* __restrict__ g1, const void* __restrict__ be1,
    const void* __restrict__ mn1, const void* __restrict__ vr1,
    const int* __restrict__ flag, bf16* __restrict__ hout, int N) {
  const int isbf = flag[0];
  const int tid = threadIdx.x, lane = tid & 63, wv = tid >> 6;
  const int m16 = lane & 15, quad = lane >> 4;
  const int row0 = blockIdx.x * 64 + wv * 16;
  const int m = row0 + m16;
  const int mc = (m < N) ? m : (N - 1);     // clamp: rows >= N never stored
  const int bi = bidx[mc];

  // ---- A fragments: x[mc][ks*32 + quad*8 .. +7], ks=0..5 (192 = 128|64) ----
  short8 af[6];
  if (isbf) {
    const bf16* xr = (const bf16*)xt + (size_t)mc * 128 + quad * 8;
#pragma unroll
    for (int ks = 0; ks < 4; ++ks) af[ks] = *(const short8*)(xr + ks * 32);
    const bf16* sr = (const bf16*)xsg + (size_t)bi * 64 + quad * 8;
    af[4] = *(const short8*)sr;
    af[5] = *(const short8*)(sr + 32);
  } else {
    const float* xr = (const float*)xt + (size_t)mc * 128 + quad * 8;
#pragma unroll
    for (int ks = 0; ks < 4; ++ks) af[ks] = pack8f(xr + ks * 32);
    const float* sr = (const float*)xsg + (size_t)bi * 64 + quad * 8;
    af[4] = pack8f(sr);
    af[5] = pack8f(sr + 32);
  }

  f32x4 acc[8];
#pragma unroll
  for (int ct = 0; ct < 8; ++ct) acc[ct] = (f32x4){0.f, 0.f, 0.f, 0.f};

  if (isbf) {
    const bf16* wb = (const bf16*)W1;
#pragma unroll
    for (int ks = 0; ks < 6; ++ks) {
      const int k = ks * 32 + quad * 8;
#pragma unroll
      for (int ct = 0; ct < 8; ++ct) {
        const int o = ct * 16 + m16;
        short8 bfrag = *(const short8*)(wb + (size_t)o * 192 + k);
        acc[ct] = __builtin_amdgcn_mfma_f32_16x16x32_bf16(af[ks], bfrag, acc[ct], 0, 0, 0);
      }
    }
  } else {
    const float* wb = (const float*)W1;
#pragma unroll
    for (int ks = 0; ks < 6; ++ks) {
      const int k = ks * 32 + quad * 8;
#pragma unroll
      for (int ct = 0; ct < 8; ++ct) {
        const int o = ct * 16 + m16;
        short8 bfrag = pack8f(wb + (size_t)o * 192 + k);
        acc[ct] = __builtin_amdgcn_mfma_f32_16x16x32_bf16(af[ks], bfrag, acc[ct], 0, 0, 0);
      }
    }
  }

  // ---- epilogue: BN + leaky, store bf16. D: col=lane&15, row=quad*4+r ----
#pragma unroll
  for (int ct = 0; ct < 8; ++ct) {
    const int o = ct * 16 + m16;
    float k1 = ld1(g1, o, isbf) * rsqrtf(ld1(vr1, o, isbf) + EPS);
    float k0 = ld1(be1, o, isbf) - ld1(mn1, o, isbf) * k1;
    float bias = ld1(b1, o, isbf);
#pragma unroll
    for (int r = 0; r < 4; ++r) {
      int mr = row0 + quad * 4 + r;
      if (mr < N) {
        float v = (acc[ct][r] + bias) * k1 + k0;
        v = (v >= 0.f) ? v : NSLOPE * v;
        hout[(size_t)mr * 128 + o] = __float2bfloat16(v);
      }
    }
  }
}

// ---------------------------------------------------------------------------
// K2: x_stat_out = leaky(bn2(x_stat @ W2^T + b2))
// ---------------------------------------------------------------------------
__global__ __launch_bounds__(64) void stat_kernel(
    const void* __restrict__ xstat, const void* __restrict__ W2,
    const void* __restrict__ b2, const void* __restrict__ g2,
    const void* __restrict__ be2, const void* __restrict__ mn2,
    const void* __restrict__ vr2, const int* __restrict__ flag,
    void* __restrict__ out, long long obase) {
  __shared__ float xs[64];
  const int isbf = flag[0];
  const int b = blockIdx.x, o = threadIdx.x;
  xs[o] = ld1(xstat, b * 64 + o, isbf);
  __syncthreads();
  float acc = ld1(b2, o, isbf);
#pragma unroll 8
  for (int j = 0; j < 64; ++j) acc += xs[j] * ld1(W2, o * 64 + j, isbf);
  float k1 = ld1(g2, o, isbf) * rsqrtf(ld1(vr2, o, isbf) + EPS);
  float k0 = ld1(be2, o, isbf) - ld1(mn2, o, isbf) * k1;
  float v = acc * k1 + k0;
  v = (v >= 0.f) ? v : NSLOPE * v;
  st1(out, (size_t)(obase + b * 64 + o), isbf, v);
}

// ---------------------------------------------------------------------------
// K3: MFMA attention. One block = 16 query rows of one batch, 4 waves.
// Phase 1: S = QK^T (prefetched K-frags, branch-free active loop; pad tail
//          zero-filled separately). Phase 2: softmax in VGPRs (STATIC 16-elem
//          arrays — no scratch) + temp_attn, P -> bf16 in Ss. Phase 3: PV.
// ---------------------------------------------------------------------------
__global__ __launch_bounds__(256) void attn_mfma_kernel(
    const void* __restrict__ ta, const bf16* __restrict__ h,
    const int* __restrict__ rs_arr, const int* __restrict__ ln_arr,
    const int* __restrict__ flag, void* __restrict__ xout, int T, int N) {
  __shared__ __align__(16) unsigned short Ss[16][1032];  // stride 516 dwords
  __shared__ __align__(16) unsigned short vT[128][66];   // stride 33 dwords

  const int b = blockIdx.y, t0 = blockIdx.x * 16;
  const int len = ln_arr[b];
  if (t0 >= len) return;              // uniform exit before any barrier
  const int isbf = flag[0];
  const int rs = rs_arr[b];
  const int nrows = min(16, len - t0);
  const int tid = threadIdx.x;
  const int lane = tid & 63, wv = tid >> 6;
  const int m16 = lane & 15, quad = lane >> 4;

  // ---- Q fragments (A operand): A[m][k], m=lane&15, k=quad*8+j ----
  short8 qf[4];
  {
    int qrow = rs + t0 + m16;
    if (qrow > N - 1) qrow = N - 1;   // clamp: value unused for t>=len rows
    const bf16* qp = h + (size_t)qrow * 128 + quad * 8;
#pragma unroll
    for (int ks = 0; ks < 4; ++ks)
      qf[ks] = *(const short8*)(qp + ks * 32);
  }

  const float scale = 0.08838834764831845f;   // 1/sqrt(128)
  const int ntiles = (T + 15) >> 4;
  const int nact = min(ntiles, (len + 15) >> 4);
  const short8 zero8 = {0, 0, 0, 0, 0, 0, 0, 0};

  // -------- phase 1: logits (active tiles, prefetched) --------
  {
    short8 kc[4] = {zero8, zero8, zero8, zero8};
    int st = wv;
    if (st < nact) {
      int s = st * 16 + m16;
      bool v = (s < len);
      const bf16* kp = h + (size_t)(rs + (v ? s : 0)) * 128 + quad * 8;
#pragma unroll
      for (int ks = 0; ks < 4; ++ks) kc[ks] = v ? *(const short8*)(kp + ks * 32) : zero8;
    }
    for (; st < nact; st += 4) {
      // prefetch next tile's K-frags
      short8 kn[4] = {zero8, zero8, zero8, zero8};
      int stn = st + 4;
      if (stn < nact) {
        int s2 = stn * 16 + m16;
        bool v2 = (s2 < len);
        const bf16* kp2 = h + (size_t)(rs + (v2 ? s2 : 0)) * 128 + quad * 8;
#pragma unroll
        for (int ks = 0; ks < 4; ++ks) kn[ks] = v2 ? *(const short8*)(kp2 + ks * 32) : zero8;
      }
      f32x4 acc = {0.f, 0.f, 0.f, 0.f};
#pragma unroll
      for (int ks = 0; ks < 4; ++ks)
        acc = __builtin_amdgcn_mfma_f32_16x16x32_bf16(qf[ks], kc[ks], acc, 0, 0, 0);
      int s = st * 16 + m16;
      if (s < T) {
#pragma unroll
        for (int r = 0; r < 4; ++r)
          Ss[quad * 4 + r][s] = __half_as_ushort(__float2half(acc[r] * scale));
      }
#pragma unroll
      for (int ks = 0; ks < 4; ++ks) kc[ks] = kn[ks];
    }
    // pad tail tiles: exact zero logits
    int st2 = nact + (((wv - nact) % 4) + 4) % 4;
    for (; st2 < ntiles; st2 += 4) {
      int s = st2 * 16 + m16;
      if (s < T) {
#pragma unroll
        for (int r = 0; r < 4; ++r) Ss[quad * 4 + r][s] = 0;
      }
    }
  }
  __syncthreads();

  // -------- phase 2: softmax (static VGPR arrays) + temp_attn -> P bf16 ----
  {
    const int Tpad = (T + 63) & ~63;
    for (int j = 0; j < 4; ++j) {
      int r = wv + (j << 2);
      float vals[16];
#pragma unroll
      for (int k = 0; k < 16; ++k) {
        int s = lane + (k << 6);
        vals[k] = (s < T) ? __half2float(__ushort_as_half(Ss[r][s])) : -INFINITY;
      }
      float mx = -INFINITY;
#pragma unroll
      for (int k = 0; k < 16; ++k) mx = fmaxf(mx, vals[k]);
#pragma unroll
      for (int off = 32; off >= 1; off >>= 1) mx = fmaxf(mx, __shfl_xor(mx, off, 64));
      float l = 0.f;
#pragma unroll
      for (int k = 0; k < 16; ++k) { vals[k] = __expf(vals[k] - mx); l += vals[k]; }
#pragma unroll
      for (int off = 32; off >= 1; off >>= 1) l += __shfl_xor(l, off, 64);
      float inv = 1.f / l;
      size_t tabase = ((size_t)b * T + (t0 + r)) * (size_t)T;
      if (isbf) {
        const bf16* tp = (const bf16*)ta + tabase;
#pragma unroll
        for (int k = 0; k < 16; ++k) {
          int s = lane + (k << 6);
          if (s < Tpad) {
            float p = 0.f;
            if (s < T) p = vals[k] * inv + b2f(tp[s]);
            *(bf16*)&Ss[r][s] = __float2bfloat16(p);
          }
        }
      } else {
        const float* tp = (const float*)ta + tabase;
#pragma unroll
        for (int k = 0; k < 16; ++k) {
          int s = lane + (k << 6);
          if (s < Tpad) {
            float p = 0.f;
            if (s < T) p = vals[k] * inv + tp[s];
            *(bf16*)&Ss[r][s] = __float2bfloat16(p);
          }
        }
      }
    }
  }
  __syncthreads();

  // -------- phase 3: O = P V --------
  f32x4 oacc0 = {0.f, 0.f, 0.f, 0.f};
  f32x4 oacc1 = {0.f, 0.f, 0.f, 0.f};
  for (int s0 = 0; s0 < len; s0 += 64) {
    for (int e = tid; e < 512; e += 256) {
      int sp = e >> 4, c8 = (e & 15) << 3;
      int s = s0 + 2 * sp;
      uint4 u0 = {0, 0, 0, 0}, u1 = {0, 0, 0, 0};
      if (s < len)     u0 = *(const uint4*)(h + (size_t)(rs + s) * 128 + c8);
      if (s + 1 < len) u1 = *(const uint4*)(h + (size_t)(rs + s + 1) * 128 + c8);
      const unsigned short* a0 = (const unsigned short*)&u0;
      const unsigned short* a1 = (const unsigned short*)&u1;
#pragma unroll
      for (int j = 0; j < 8; ++j)
        *(unsigned*)&vT[c8 + j][2 * sp] = (unsigned)a0[j] | ((unsigned)a1[j] << 16);
    }
    __syncthreads();
#pragma unroll
    for (int ks = 0; ks < 2; ++ks) {
      short8 af = *(const short8*)&Ss[m16][s0 + ks * 32 + quad * 8];
#pragma unroll
      for (int ct = 0; ct < 2; ++ct) {
        const int c0 = wv * 32 + ct * 16;
        const unsigned short* vrow = &vT[c0 + m16][ks * 32 + quad * 8];
        unsigned w0 = *(const unsigned*)(vrow + 0);
        unsigned w1 = *(const unsigned*)(vrow + 2);
        unsigned w2 = *(const unsigned*)(vrow + 4);
        unsigned w3 = *(const unsigned*)(vrow + 6);
        short8 bfv;
        bfv[0] = (short)(w0 & 0xffffu); bfv[1] = (short)(w0 >> 16);
        bfv[2] = (short)(w1 & 0xffffu); bfv[3] = (short)(w1 >> 16);
        bfv[4] = (short)(w2 & 0xffffu); bfv[5] = (short)(w2 >> 16);
        bfv[6] = (short)(w3 & 0xffffu); bfv[7] = (short)(w3 >> 16);
        if (ct == 0)
          oacc0 = __builtin_amdgcn_mfma_f32_16x16x32_bf16(af, bfv, oacc0, 0, 0, 0);
        else
          oacc1 = __builtin_amdgcn_mfma_f32_16x16x32_bf16(af, bfv, oacc1, 0, 0, 0);
      }
    }
    __syncthreads();
  }

  // epilogue: D col = lane&15 (= output col), row = quad*4 + r (= t)
#pragma unroll
  for (int r = 0; r < 4; ++r) {
    int t = quad * 4 + r;
    if (t < nrows) {
      size_t ob = (size_t)(rs + t0 + t) * 128;
      st1(xout, ob + wv * 32 + m16,      isbf, oacc0[r]);
      st1(xout, ob + wv * 32 + 16 + m16, isbf, oacc1[r]);
    }
  }
}

// ---------------------------------------------------------------------------
extern "C" void kernel_launch(void* const* d_in, const int* in_sizes, int n_in,
                              void* d_out, int out_size, void* d_ws, size_t ws_size,
                              hipStream_t stream) {
  const void* x_temp    = d_in[0];
  const void* x_stat    = d_in[1];
  const void* temp_attn = d_in[2];
  const int N = in_sizes[0] / 128;      // 23450
  const int B = in_sizes[1] / 64;       // 32
  long long tt = (long long)in_sizes[2] / B;
  int T = 1; while ((long long)(T + 1) * (T + 1) <= tt) ++T;  // isqrt -> 1024

  int p = 3;
  while (p < n_in && in_sizes[p] != N) ++p;
  const int* batch_idx = (const int*)d_in[p++];
  const int* pos_idx   = (const int*)d_in[p++];
  const void* W1 = d_in[p++];
  const void* b1 = d_in[p++];
  const void* g1 = d_in[p++];
  const void* be1= d_in[p++];
  const void* mn1= d_in[p++];
  const void* vr1= d_in[p++];
  const void* W2 = d_in[p++];
  const void* b2 = d_in[p++];
  const void* g2 = d_in[p++];
  const void* be2= d_in[p++];
  const void* mn2= d_in[p++];
  const void* vr2= d_in[p++];

  int*  meta = (int*)d_ws;
  int*  rs   = meta;
  int*  lnp  = meta + B;
  int*  flag = meta + 2 * B;
  bf16* h    = (bf16*)((char*)d_ws + 1024);
  size_t need = 1024 + (size_t)N * 128 * sizeof(bf16);

  long long obase = (long long)N * 128;

  meta_kernel<<<90, 256, 0, stream>>>(x_temp, batch_idx, pos_idx, N, B, rs, lnp, flag);
  stat_kernel<<<B, 64, 0, stream>>>(x_stat, W2, b2, g2, be2, mn2, vr2, flag,
                                    d_out, obase);
  if (ws_size >= need) {
    h_mfma_kernel<<<(N + 63) / 64, 256, 0, stream>>>(x_temp, x_stat, batch_idx,
                                                     W1, b1, g1, be1, mn1, vr1,
                                                     flag, h, N);
    attn_mfma_kernel<<<dim3((T + 15) / 16, B), 256, 0, stream>>>(
        temp_attn, h, rs, lnp, flag, d_out, T, N);
  } else {
    zfill_kernel<<<512, 256, 0, stream>>>(d_out, flag, obase);
  }
}

// Round 6
// 442.536 us; speedup vs baseline: 2.3716x; 1.1178x over previous
//
#include <hip/hip_runtime.h>
#include <hip/hip_bf16.h>
#include <hip/hip_fp16.h>

typedef __hip_bfloat16 bf16;
typedef __attribute__((ext_vector_type(8))) short short8;
typedef __attribute__((ext_vector_type(4))) float f32x4;

#define EPS 1e-5f
#define NSLOPE 0.01f

__device__ __forceinline__ float b2f(bf16 v) { return __bfloat162float(v); }

__device__ __forceinline__ float ld1(const void* p, size_t idx, int isbf) {
  if (isbf) return b2f(((const bf16*)p)[idx]);
  return ((const float*)p)[idx];
}
__device__ __forceinline__ void st1(void* p, size_t idx, int isbf, float v) {
  if (isbf) ((bf16*)p)[idx] = __float2bfloat16(v);
  else      ((float*)p)[idx] = v;
}
__device__ __forceinline__ short f2bs(float x) {
  bf16 t = __float2bfloat16(x);
  short s; __builtin_memcpy(&s, &t, 2); return s;
}
// pack 8 consecutive floats -> short8 of bf16
__device__ __forceinline__ short8 pack8f(const float* p) {
  float4 a = *(const float4*)p, b = *(const float4*)(p + 4);
  short8 r;
  r[0] = f2bs(a.x); r[1] = f2bs(a.y); r[2] = f2bs(a.z); r[3] = f2bs(a.w);
  r[4] = f2bs(b.x); r[5] = f2bs(b.y); r[6] = f2bs(b.z); r[7] = f2bs(b.w);
  return r;
}

// ---------------------------------------------------------------------------
// K0: meta (row_start, len per batch) + input-dtype sniffer (block 0 only).
// ---------------------------------------------------------------------------
__global__ void meta_kernel(const void* __restrict__ xt,
                            const int* __restrict__ bidx, const int* __restrict__ pidx,
                            int N, int B, int* __restrict__ rs, int* __restrict__ ln,
                            int* __restrict__ flag) {
  if (blockIdx.x == 0 && threadIdx.x < 64) {
    unsigned w = ((const unsigned*)xt)[threadIdx.x];
    unsigned lo = w & 0xffffu;
    unsigned ex = (lo >> 7) & 0xffu;
    bool sane = ((lo & 0x7fffu) == 0u) || (ex >= 96u && ex <= 134u);
    unsigned long long m = __ballot(sane);
    if (threadIdx.x == 0) flag[0] = (__popcll(m) >= 48) ? 1 : 0;
  }
  int stride = gridDim.x * blockDim.x;
  for (int i = blockIdx.x * blockDim.x + threadIdx.x; i < N; i += stride) {
    int b = bidx[i];
    if ((unsigned)b >= (unsigned)B) continue;
    if (i == 0 || bidx[i - 1] != b) rs[b] = i;
    if (i == N - 1 || bidx[i + 1] != b) ln[b] = pidx[i] + 1;
  }
}

// ---------------------------------------------------------------------------
// K0b: one-time W1 -> bf16 conversion into ws (kills per-wave repack in K1)
// ---------------------------------------------------------------------------
__global__ void w1cvt_kernel(const void* __restrict__ W1, const int* __restrict__ flag,
                             bf16* __restrict__ w1b, int n) {
  const int isbf = flag[0];
  int i = blockIdx.x * blockDim.x + threadIdx.x;
  if (i < n) w1b[i] = __float2bfloat16(ld1(W1, i, isbf));
}

// ---------------------------------------------------------------------------
// Kf: flag-aware zero fill of x_out (fallback when ws too small)
// ---------------------------------------------------------------------------
__global__ void zfill_kernel(void* out, const int* __restrict__ flag, long long n) {
  const int isbf = flag[0];
  long long i = (long long)blockIdx.x * blockDim.x + threadIdx.x;
  long long stride = (long long)gridDim.x * blockDim.x;
  for (; i < n; i += stride) st1(out, (size_t)i, isbf, 0.f);
}

// ---------------------------------------------------------------------------
// K1: h = leaky(bn1(concat(x_temp, x_stat[bidx]) @ W1^T + b1))  via MFMA.
// Block = 64 rows x 128 cols, 4 waves. B-frags from pre-converted bf16 W1.
// ---------------------------------------------------------------------------
__global__ __launch_bounds__(256) void h_mfma_kernel(
    const void* __restrict__ xt, const void* __restrict__ xsg,
    const int* __restrict__ bidx, const bf16* __restrict__ w1b,
    const void* __restrict__ b1,
    const void* __restrict__ g1, const void* __restrict__ be1,
    const void* __restrict__ mn1, const void* __restrict__ vr1,
    const int* __restrict__ flag, bf16* __restrict__ hout, int N) {
  const int isbf = flag[0];
  const int tid = threadIdx.x, lane = tid & 63, wv = tid >> 6;
  const int m16 = lane & 15, quad = lane >> 4;
  const int row0 = blockIdx.x * 64 + wv * 16;
  const int m = row0 + m16;
  const int mc = (m < N) ? m : (N - 1);     // clamp: rows >= N never stored
  const int bi = bidx[mc];

  // ---- A fragments: x[mc][ks*32 + quad*8 .. +7], ks=0..5 (192 = 128|64) ----
  short8 af[6];
  if (isbf) {
    const bf16* xr = (const bf16*)xt + (size_t)mc * 128 + quad * 8;
#pragma unroll
    for (int ks = 0; ks < 4; ++ks) af[ks] = *(const short8*)(xr + ks * 32);
    const bf16* sr = (const bf16*)xsg + (size_t)bi * 64 + quad * 8;
    af[4] = *(const short8*)sr;
    af[5] = *(const short8*)(sr + 32);
  } else {
    const float* xr = (const float*)xt + (size_t)mc * 128 + quad * 8;
#pragma unroll
    for (int ks = 0; ks < 4; ++ks) af[ks] = pack8f(xr + ks * 32);
    const float* sr = (const float*)xsg + (size_t)bi * 64 + quad * 8;
    af[4] = pack8f(sr);
    af[5] = pack8f(sr + 32);
  }

  f32x4 acc[8];
#pragma unroll
  for (int ct = 0; ct < 8; ++ct) acc[ct] = (f32x4){0.f, 0.f, 0.f, 0.f};

#pragma unroll
  for (int ks = 0; ks < 6; ++ks) {
    const int k = ks * 32 + quad * 8;
#pragma unroll
    for (int ct = 0; ct < 8; ++ct) {
      const int o = ct * 16 + m16;
      short8 bfrag = *(const short8*)(w1b + (size_t)o * 192 + k);
      acc[ct] = __builtin_amdgcn_mfma_f32_16x16x32_bf16(af[ks], bfrag, acc[ct], 0, 0, 0);
    }
  }

  // ---- epilogue: BN + leaky, store bf16. D: col=lane&15, row=quad*4+r ----
#pragma unroll
  for (int ct = 0; ct < 8; ++ct) {
    const int o = ct * 16 + m16;
    float k1 = ld1(g1, o, isbf) * rsqrtf(ld1(vr1, o, isbf) + EPS);
    float k0 = ld1(be1, o, isbf) - ld1(mn1, o, isbf) * k1;
    float bias = ld1(b1, o, isbf);
#pragma unroll
    for (int r = 0; r < 4; ++r) {
      int mr = row0 + quad * 4 + r;
      if (mr < N) {
        float v = (acc[ct][r] + bias) * k1 + k0;
        v = (v >= 0.f) ? v : NSLOPE * v;
        hout[(size_t)mr * 128 + o] = __float2bfloat16(v);
      }
    }
  }
}

// ---------------------------------------------------------------------------
// K2: x_stat_out = leaky(bn2(x_stat @ W2^T + b2))
// ---------------------------------------------------------------------------
__global__ __launch_bounds__(64) void stat_kernel(
    const void* __restrict__ xstat, const void* __restrict__ W2,
    const void* __restrict__ b2, const void* __restrict__ g2,
    const void* __restrict__ be2, const void* __restrict__ mn2,
    const void* __restrict__ vr2, const int* __restrict__ flag,
    void* __restrict__ out, long long obase) {
  __shared__ float xs[64];
  const int isbf = flag[0];
  const int b = blockIdx.x, o = threadIdx.x;
  xs[o] = ld1(xstat, b * 64 + o, isbf);
  __syncthreads();
  float acc = ld1(b2, o, isbf);
#pragma unroll 8
  for (int j = 0; j < 64; ++j) acc += xs[j] * ld1(W2, o * 64 + j, isbf);
  float k1 = ld1(g2, o, isbf) * rsqrtf(ld1(vr2, o, isbf) + EPS);
  float k0 = ld1(be2, o, isbf) - ld1(mn2, o, isbf) * k1;
  float v = acc * k1 + k0;
  v = (v >= 0.f) ? v : NSLOPE * v;
  st1(out, (size_t)(obase + b * 64 + o), isbf, v);
}

// ---------------------------------------------------------------------------
// K3: MFMA attention. x_out = softmax(QK^T) @ V + ta @ V  (fused in phase 3).
// Block = 16 query rows of one batch, 4 waves.
// Phase 1: S = QK^T, prefetched K-frags, active tiles only.
// Phase 2: softmax in VGPRs over s<len with ANALYTIC zero-pad term; P -> bf16
//          in Ss, tail [len, ceil64(len)) zero-filled. No global loads.
// Phase 3: per V-chunk, TWO A-operands stream through MFMA: P (from LDS) and
//          ta (from global, coalesced 16B loads). Masking is free: V rows
//          >= len are zeroed; t >= len outputs never stored.
// ---------------------------------------------------------------------------
__global__ __launch_bounds__(256) void attn_mfma_kernel(
    const void* __restrict__ ta, const bf16* __restrict__ h,
    const int* __restrict__ rs_arr, const int* __restrict__ ln_arr,
    const int* __restrict__ flag, void* __restrict__ xout, int T, int N) {
  __shared__ __align__(16) unsigned short Ss[16][1032];  // stride 516 dwords
  __shared__ __align__(16) unsigned short vT[128][66];   // stride 33 dwords

  const int b = blockIdx.y, t0 = blockIdx.x * 16;
  const int len = ln_arr[b];
  if (t0 >= len) return;              // uniform exit before any barrier
  const int isbf = flag[0];
  const int rs = rs_arr[b];
  const int nrows = min(16, len - t0);
  const int tid = threadIdx.x;
  const int lane = tid & 63, wv = tid >> 6;
  const int m16 = lane & 15, quad = lane >> 4;

  // ---- Q fragments (A operand): A[m][k], m=lane&15, k=quad*8+j ----
  short8 qf[4];
  {
    int qrow = rs + t0 + m16;
    if (qrow > N - 1) qrow = N - 1;   // clamp: value unused for t>=len rows
    const bf16* qp = h + (size_t)qrow * 128 + quad * 8;
#pragma unroll
    for (int ks = 0; ks < 4; ++ks)
      qf[ks] = *(const short8*)(qp + ks * 32);
  }

  const float scale = 0.08838834764831845f;   // 1/sqrt(128)
  const int nact = (len + 15) >> 4;           // active 16-tiles
  const short8 zero8 = {0, 0, 0, 0, 0, 0, 0, 0};

  // -------- phase 1: logits (active tiles, prefetched) --------
  {
    short8 kc[4] = {zero8, zero8, zero8, zero8};
    int st = wv;
    if (st < nact) {
      int s = st * 16 + m16;
      bool v = (s < len);
      const bf16* kp = h + (size_t)(rs + (v ? s : 0)) * 128 + quad * 8;
#pragma unroll
      for (int ks = 0; ks < 4; ++ks) kc[ks] = v ? *(const short8*)(kp + ks * 32) : zero8;
    }
    for (; st < nact; st += 4) {
      short8 kn[4] = {zero8, zero8, zero8, zero8};
      int stn = st + 4;
      if (stn < nact) {
        int s2 = stn * 16 + m16;
        bool v2 = (s2 < len);
        const bf16* kp2 = h + (size_t)(rs + (v2 ? s2 : 0)) * 128 + quad * 8;
#pragma unroll
        for (int ks = 0; ks < 4; ++ks) kn[ks] = v2 ? *(const short8*)(kp2 + ks * 32) : zero8;
      }
      f32x4 acc = {0.f, 0.f, 0.f, 0.f};
#pragma unroll
      for (int ks = 0; ks < 4; ++ks)
        acc = __builtin_amdgcn_mfma_f32_16x16x32_bf16(qf[ks], kc[ks], acc, 0, 0, 0);
      int s = st * 16 + m16;
      if (s < T) {
#pragma unroll
        for (int r = 0; r < 4; ++r)
          Ss[quad * 4 + r][s] = __half_as_ushort(__float2half(acc[r] * scale));
      }
#pragma unroll
      for (int ks = 0; ks < 4; ++ks) kc[ks] = kn[ks];
    }
  }
  __syncthreads();

  // -------- phase 2: softmax (VGPR-static, analytic pad) -> P bf16 --------
  {
    const int lenp64 = (len + 63) & ~63;
    for (int j = 0; j < 4; ++j) {
      int r = wv + (j << 2);
      float vals[16];
#pragma unroll
      for (int k = 0; k < 16; ++k) {
        int s = lane + (k << 6);
        vals[k] = (s < len) ? __half2float(__ushort_as_half(Ss[r][s])) : -INFINITY;
      }
      float mx = -INFINITY;
#pragma unroll
      for (int k = 0; k < 16; ++k) mx = fmaxf(mx, vals[k]);
#pragma unroll
      for (int off = 32; off >= 1; off >>= 1) mx = fmaxf(mx, __shfl_xor(mx, off, 64));
      if (len < T) mx = fmaxf(mx, 0.f);       // padded zero logits join the max
      float l = 0.f;
#pragma unroll
      for (int k = 0; k < 16; ++k) { float e = __expf(vals[k] - mx); vals[k] = e; l += e; }
#pragma unroll
      for (int off = 32; off >= 1; off >>= 1) l += __shfl_xor(l, off, 64);
      l += (float)(T - len) * __expf(-mx);    // analytic padded-zero mass
      float inv = 1.f / l;
#pragma unroll
      for (int k = 0; k < 16; ++k) {
        int s = lane + (k << 6);
        if (s < len)          *(bf16*)&Ss[r][s] = __float2bfloat16(vals[k] * inv);
        else if (s < lenp64)  *(bf16*)&Ss[r][s] = __float2bfloat16(0.f);
      }
    }
  }
  __syncthreads();

  // -------- phase 3: O = P V + ta V --------
  f32x4 oacc0 = {0.f, 0.f, 0.f, 0.f};
  f32x4 oacc1 = {0.f, 0.f, 0.f, 0.f};
  const size_t tarow = ((size_t)b * T + (t0 + m16)) * (size_t)T;
  for (int s0 = 0; s0 < len; s0 += 64) {
    // stage vT: rows c (128), cols s-s0 (64); zero for s >= len
    for (int e = tid; e < 512; e += 256) {
      int sp = e >> 4, c8 = (e & 15) << 3;
      int s = s0 + 2 * sp;
      uint4 u0 = {0, 0, 0, 0}, u1 = {0, 0, 0, 0};
      if (s < len)     u0 = *(const uint4*)(h + (size_t)(rs + s) * 128 + c8);
      if (s + 1 < len) u1 = *(const uint4*)(h + (size_t)(rs + s + 1) * 128 + c8);
      const unsigned short* a0 = (const unsigned short*)&u0;
      const unsigned short* a1 = (const unsigned short*)&u1;
#pragma unroll
      for (int j = 0; j < 8; ++j)
        *(unsigned*)&vT[c8 + j][2 * sp] = (unsigned)a0[j] | ((unsigned)a1[j] << 16);
    }
    // ta A-frags for this chunk (global, overlaps with barrier wait)
    short8 taf0, taf1;
    if (isbf) {
      const bf16* tp = (const bf16*)ta + tarow + s0 + quad * 8;
      taf0 = *(const short8*)tp;
      taf1 = *(const short8*)(tp + 32);
    } else {
      const float* tp = (const float*)ta + tarow + s0 + quad * 8;
      taf0 = pack8f(tp);
      taf1 = pack8f(tp + 32);
    }
    __syncthreads();
#pragma unroll
    for (int ks = 0; ks < 2; ++ks) {
      short8 pf = *(const short8*)&Ss[m16][s0 + ks * 32 + quad * 8];
      short8 tf = ks ? taf1 : taf0;
#pragma unroll
      for (int ct = 0; ct < 2; ++ct) {
        const int c0 = wv * 32 + ct * 16;
        const unsigned short* vrow = &vT[c0 + m16][ks * 32 + quad * 8];
        unsigned w0 = *(const unsigned*)(vrow + 0);
        unsigned w1 = *(const unsigned*)(vrow + 2);
        unsigned w2 = *(const unsigned*)(vrow + 4);
        unsigned w3 = *(const unsigned*)(vrow + 6);
        short8 bfv;
        bfv[0] = (short)(w0 & 0xffffu); bfv[1] = (short)(w0 >> 16);
        bfv[2] = (short)(w1 & 0xffffu); bfv[3] = (short)(w1 >> 16);
        bfv[4] = (short)(w2 & 0xffffu); bfv[5] = (short)(w2 >> 16);
        bfv[6] = (short)(w3 & 0xffffu); bfv[7] = (short)(w3 >> 16);
        if (ct == 0) {
          oacc0 = __builtin_amdgcn_mfma_f32_16x16x32_bf16(pf, bfv, oacc0, 0, 0, 0);
          oacc0 = __builtin_amdgcn_mfma_f32_16x16x32_bf16(tf, bfv, oacc0, 0, 0, 0);
        } else {
          oacc1 = __builtin_amdgcn_mfma_f32_16x16x32_bf16(pf, bfv, oacc1, 0, 0, 0);
          oacc1 = __builtin_amdgcn_mfma_f32_16x16x32_bf16(tf, bfv, oacc1, 0, 0, 0);
        }
      }
    }
    __syncthreads();
  }

  // epilogue: D col = lane&15 (= output col), row = quad*4 + r (= t)
#pragma unroll
  for (int r = 0; r < 4; ++r) {
    int t = quad * 4 + r;
    if (t < nrows) {
      size_t ob = (size_t)(rs + t0 + t) * 128;
      st1(xout, ob + wv * 32 + m16,      isbf, oacc0[r]);
      st1(xout, ob + wv * 32 + 16 + m16, isbf, oacc1[r]);
    }
  }
}

// ---------------------------------------------------------------------------
extern "C" void kernel_launch(void* const* d_in, const int* in_sizes, int n_in,
                              void* d_out, int out_size, void* d_ws, size_t ws_size,
                              hipStream_t stream) {
  const void* x_temp    = d_in[0];
  const void* x_stat    = d_in[1];
  const void* temp_attn = d_in[2];
  const int N = in_sizes[0] / 128;      // 23450
  const int B = in_sizes[1] / 64;       // 32
  long long tt = (long long)in_sizes[2] / B;
  int T = 1; while ((long long)(T + 1) * (T + 1) <= tt) ++T;  // isqrt -> 1024

  int p = 3;
  while (p < n_in && in_sizes[p] != N) ++p;
  const int* batch_idx = (const int*)d_in[p++];
  const int* pos_idx   = (const int*)d_in[p++];
  const void* W1 = d_in[p++];
  const void* b1 = d_in[p++];
  const void* g1 = d_in[p++];
  const void* be1= d_in[p++];
  const void* mn1= d_in[p++];
  const void* vr1= d_in[p++];
  const void* W2 = d_in[p++];
  const void* b2 = d_in[p++];
  const void* g2 = d_in[p++];
  const void* be2= d_in[p++];
  const void* mn2= d_in[p++];
  const void* vr2= d_in[p++];

  int*  meta = (int*)d_ws;
  int*  rs   = meta;
  int*  lnp  = meta + B;
  int*  flag = meta + 2 * B;
  bf16* h    = (bf16*)((char*)d_ws + 1024);
  bf16* w1b  = h + (size_t)N * 128;
  const int w1n = 128 * 192;
  size_t need = 1024 + (size_t)N * 128 * sizeof(bf16) + (size_t)w1n * sizeof(bf16);

  long long obase = (long long)N * 128;

  meta_kernel<<<90, 256, 0, stream>>>(x_temp, batch_idx, pos_idx, N, B, rs, lnp, flag);
  stat_kernel<<<B, 64, 0, stream>>>(x_stat, W2, b2, g2, be2, mn2, vr2, flag,
                                    d_out, obase);
  if (ws_size >= need) {
    w1cvt_kernel<<<(w1n + 255) / 256, 256, 0, stream>>>(W1, flag, w1b, w1n);
    h_mfma_kernel<<<(N + 63) / 64, 256, 0, stream>>>(x_temp, x_stat, batch_idx,
                                                     w1b, b1, g1, be1, mn1, vr1,
                                                     flag, h, N);
    attn_mfma_kernel<<<dim3((T + 15) / 16, B), 256, 0, stream>>>(
        temp_attn, h, rs, lnp, flag, d_out, T, N);
  } else {
    zfill_kernel<<<512, 256, 0, stream>>>(d_out, flag, obase);
  }
}

// Round 7
// 424.428 us; speedup vs baseline: 2.4727x; 1.0427x over previous
//
#include <hip/hip_runtime.h>
#include <hip/hip_bf16.h>
#include <hip/hip_fp16.h>

typedef __hip_bfloat16 bf16;
typedef __attribute__((ext_vector_type(8))) short short8;
typedef __attribute__((ext_vector_type(4))) float f32x4;

#define EPS 1e-5f
#define NSLOPE 0.01f

__device__ __forceinline__ float b2f(bf16 v) { return __bfloat162float(v); }

__device__ __forceinline__ float ld1(const void* p, size_t idx, int isbf) {
  if (isbf) return b2f(((const bf16*)p)[idx]);
  return ((const float*)p)[idx];
}
__device__ __forceinline__ void st1(void* p, size_t idx, int isbf, float v) {
  if (isbf) ((bf16*)p)[idx] = __float2bfloat16(v);
  else      ((float*)p)[idx] = v;
}
__device__ __forceinline__ short f2bs(float x) {
  bf16 t = __float2bfloat16(x);
  short s; __builtin_memcpy(&s, &t, 2); return s;
}
// pack 8 consecutive floats -> short8 of bf16
__device__ __forceinline__ short8 pack8f(const float* p) {
  float4 a = *(const float4*)p, b = *(const float4*)(p + 4);
  short8 r;
  r[0] = f2bs(a.x); r[1] = f2bs(a.y); r[2] = f2bs(a.z); r[3] = f2bs(a.w);
  r[4] = f2bs(b.x); r[5] = f2bs(b.y); r[6] = f2bs(b.z); r[7] = f2bs(b.w);
  return r;
}

// ---------------------------------------------------------------------------
// K0: meta (row_start, len per batch) + dtype sniffer + W1 -> bf16 convert
// ---------------------------------------------------------------------------
__global__ void meta_kernel(const void* __restrict__ xt,
                            const int* __restrict__ bidx, const int* __restrict__ pidx,
                            int N, int B, int* __restrict__ rs, int* __restrict__ ln,
                            int* __restrict__ flag,
                            const void* __restrict__ W1, bf16* __restrict__ w1b, int w1n) {
  int isbf_l = 0;
  {
    unsigned w = ((const unsigned*)xt)[threadIdx.x & 63];
    unsigned lo = w & 0xffffu;
    unsigned ex = (lo >> 7) & 0xffu;
    bool sane = ((lo & 0x7fffu) == 0u) || (ex >= 96u && ex <= 134u);
    unsigned long long m = __ballot(sane);
    isbf_l = (__popcll(m) >= 48) ? 1 : 0;
    if (blockIdx.x == 0 && threadIdx.x == 0) flag[0] = isbf_l;
  }
  int stride = gridDim.x * blockDim.x;
  int g0 = blockIdx.x * blockDim.x + threadIdx.x;
  for (int i = g0; i < N; i += stride) {
    int b = bidx[i];
    if ((unsigned)b >= (unsigned)B) continue;
    if (i == 0 || bidx[i - 1] != b) rs[b] = i;
    if (i == N - 1 || bidx[i + 1] != b) ln[b] = pidx[i] + 1;
  }
  for (int i = g0; i < w1n; i += stride)
    w1b[i] = __float2bfloat16(ld1(W1, i, isbf_l));
}

// ---------------------------------------------------------------------------
// Kf: flag-aware zero fill of x_out (fallback when ws too small)
// ---------------------------------------------------------------------------
__global__ void zfill_kernel(void* out, const int* __restrict__ flag, long long n) {
  const int isbf = flag[0];
  long long i = (long long)blockIdx.x * blockDim.x + threadIdx.x;
  long long stride = (long long)gridDim.x * blockDim.x;
  for (; i < n; i += stride) st1(out, (size_t)i, isbf, 0.f);
}

// ---------------------------------------------------------------------------
// K1: h = leaky(bn1(concat(x_temp, x_stat[bidx]) @ W1^T + b1))  via MFMA.
// ---------------------------------------------------------------------------
__global__ __launch_bounds__(256) void h_mfma_kernel(
    const void* __restrict__ xt, const void* __restrict__ xsg,
    const int* __restrict__ bidx, const bf16* __restrict__ w1b,
    const void* __restrict__ b1,
    const void* __restrict__ g1, const void* __restrict__ be1,
    const void* __restrict__ mn1, const void* __restrict__ vr1,
    const int* __restrict__ flag, bf16* __restrict__ hout, int N) {
  const int isbf = flag[0];
  const int tid = threadIdx.x, lane = tid & 63, wv = tid >> 6;
  const int m16 = lane & 15, quad = lane >> 4;
  const int row0 = blockIdx.x * 64 + wv * 16;
  const int m = row0 + m16;
  const int mc = (m < N) ? m : (N - 1);
  const int bi = bidx[mc];

  short8 af[6];
  if (isbf) {
    const bf16* xr = (const bf16*)xt + (size_t)mc * 128 + quad * 8;
#pragma unroll
    for (int ks = 0; ks < 4; ++ks) af[ks] = *(const short8*)(xr + ks * 32);
    const bf16* sr = (const bf16*)xsg + (size_t)bi * 64 + quad * 8;
    af[4] = *(const short8*)sr;
    af[5] = *(const short8*)(sr + 32);
  } else {
    const float* xr = (const float*)xt + (size_t)mc * 128 + quad * 8;
#pragma unroll
    for (int ks = 0; ks < 4; ++ks) af[ks] = pack8f(xr + ks * 32);
    const float* sr = (const float*)xsg + (size_t)bi * 64 + quad * 8;
    af[4] = pack8f(sr);
    af[5] = pack8f(sr + 32);
  }

  f32x4 acc[8];
#pragma unroll
  for (int ct = 0; ct < 8; ++ct) acc[ct] = (f32x4){0.f, 0.f, 0.f, 0.f};

#pragma unroll
  for (int ks = 0; ks < 6; ++ks) {
    const int k = ks * 32 + quad * 8;
#pragma unroll
    for (int ct = 0; ct < 8; ++ct) {
      const int o = ct * 16 + m16;
      short8 bfrag = *(const short8*)(w1b + (size_t)o * 192 + k);
      acc[ct] = __builtin_amdgcn_mfma_f32_16x16x32_bf16(af[ks], bfrag, acc[ct], 0, 0, 0);
    }
  }

#pragma unroll
  for (int ct = 0; ct < 8; ++ct) {
    const int o = ct * 16 + m16;
    float k1 = ld1(g1, o, isbf) * rsqrtf(ld1(vr1, o, isbf) + EPS);
    float k0 = ld1(be1, o, isbf) - ld1(mn1, o, isbf) * k1;
    float bias = ld1(b1, o, isbf);
#pragma unroll
    for (int r = 0; r < 4; ++r) {
      int mr = row0 + quad * 4 + r;
      if (mr < N) {
        float v = (acc[ct][r] + bias) * k1 + k0;
        v = (v >= 0.f) ? v : NSLOPE * v;
        hout[(size_t)mr * 128 + o] = __float2bfloat16(v);
      }
    }
  }
}

// ---------------------------------------------------------------------------
// K2: x_stat_out = leaky(bn2(x_stat @ W2^T + b2))
// ---------------------------------------------------------------------------
__global__ __launch_bounds__(64) void stat_kernel(
    const void* __restrict__ xstat, const void* __restrict__ W2,
    const void* __restrict__ b2, const void* __restrict__ g2,
    const void* __restrict__ be2, const void* __restrict__ mn2,
    const void* __restrict__ vr2, const int* __restrict__ flag,
    void* __restrict__ out, long long obase) {
  __shared__ float xs[64];
  const int isbf = flag[0];
  const int b = blockIdx.x, o = threadIdx.x;
  xs[o] = ld1(xstat, b * 64 + o, isbf);
  __syncthreads();
  float acc = ld1(b2, o, isbf);
#pragma unroll 8
  for (int j = 0; j < 64; ++j) acc += xs[j] * ld1(W2, o * 64 + j, isbf);
  float k1 = ld1(g2, o, isbf) * rsqrtf(ld1(vr2, o, isbf) + EPS);
  float k0 = ld1(be2, o, isbf) - ld1(mn2, o, isbf) * k1;
  float v = acc * k1 + k0;
  v = (v >= 0.f) ? v : NSLOPE * v;
  st1(out, (size_t)(obase + b * 64 + o), isbf, v);
}

// ---------------------------------------------------------------------------
// K3: fused online-softmax MFMA attention.
// Block = 16 query rows of one batch, 4 waves, s-chunks of 64.
// Per chunk: stage vT (V transposed) + prefetch next K-frags + QK MFMA ->
// cross-wave row-max (LDS stats) -> alpha-rescale P-accumulator -> P bf16
// (16x64 LDS) -> PV + taV MFMAs. Analytic zero-pad term at the end.
// LDS ~19.4 KB (was 50), launch_bounds (256,4) -> 4 blocks/CU target.
// ---------------------------------------------------------------------------
__global__ __launch_bounds__(256, 4) void attn_mfma_kernel(
    const void* __restrict__ ta, const bf16* __restrict__ h,
    const int* __restrict__ rs_arr, const int* __restrict__ ln_arr,
    const int* __restrict__ flag, void* __restrict__ xout, int T, int N) {
  __shared__ __align__(16) unsigned short vT[128][66];   // 16896 B
  __shared__ __align__(16) unsigned short Pbuf[16][72];  // 2304 B (stride 144B)
  __shared__ float wmax[4][16];
  __shared__ float wsum[4][16];
  __shared__ float mrun[16];
  __shared__ float lrun[16];

  const int b = blockIdx.y, t0 = blockIdx.x * 16;
  const int len = ln_arr[b];
  if (t0 >= len) return;              // uniform exit before any barrier
  const int isbf = flag[0];
  const int rs = rs_arr[b];
  const int nrows = min(16, len - t0);
  const int tid = threadIdx.x;
  const int lane = tid & 63, wv = tid >> 6;
  const int m16 = lane & 15, quad = lane >> 4;

  // ---- Q fragments (A operand): A[m=t][k], m=lane&15, k=quad*8+j ----
  short8 qf[4];
  {
    int qrow = rs + t0 + m16;
    if (qrow > N - 1) qrow = N - 1;   // clamp: value unused for t>=len rows
    const bf16* qp = h + (size_t)qrow * 128 + quad * 8;
#pragma unroll
    for (int ks = 0; ks < 4; ++ks) qf[ks] = *(const short8*)(qp + ks * 32);
  }

  if (tid < 16) { mrun[tid] = -INFINITY; lrun[tid] = 0.f; }

  const float scale = 0.08838834764831845f;   // 1/sqrt(128)
  const short8 zero8 = {0, 0, 0, 0, 0, 0, 0, 0};
  const int scol = wv * 16 + m16;             // this lane's s-col within chunk
  const size_t tarow = ((size_t)b * T + (t0 + m16)) * (size_t)T;

  f32x4 accp[2] = {{0.f,0.f,0.f,0.f},{0.f,0.f,0.f,0.f}};
  f32x4 acct[2] = {{0.f,0.f,0.f,0.f},{0.f,0.f,0.f,0.f}};

  // preload K-frags for chunk 0 (B operand: B[n=s][k], n=lane&15)
  short8 kf[4];
  {
    bool v = scol < len;
    const bf16* kp = h + (size_t)(rs + (v ? scol : 0)) * 128 + quad * 8;
#pragma unroll
    for (int ks = 0; ks < 4; ++ks) kf[ks] = v ? *(const short8*)(kp + ks * 32) : zero8;
  }

  for (int s0 = 0; s0 < len; s0 += 64) {
    // ---- stage vT: V rows s0..s0+63 transposed (c-major); zero past len ----
    for (int e = tid; e < 512; e += 256) {
      int sp = e >> 4, c8 = (e & 15) << 3;
      int s = s0 + 2 * sp;
      uint4 u0 = {0,0,0,0}, u1 = {0,0,0,0};
      if (s < len)     u0 = *(const uint4*)(h + (size_t)(rs + s) * 128 + c8);
      if (s + 1 < len) u1 = *(const uint4*)(h + (size_t)(rs + s + 1) * 128 + c8);
      const unsigned short* a0 = (const unsigned short*)&u0;
      const unsigned short* a1 = (const unsigned short*)&u1;
#pragma unroll
      for (int j = 0; j < 8; ++j)
        *(unsigned*)&vT[c8 + j][2 * sp] = (unsigned)a0[j] | ((unsigned)a1[j] << 16);
    }
    // ---- ta A-frags for this chunk (used after bar2; loads overlap) ----
    short8 taf0, taf1;
    if (isbf) {
      const bf16* tp = (const bf16*)ta + tarow + s0 + quad * 8;
      taf0 = *(const short8*)tp;
      taf1 = *(const short8*)(tp + 32);
    } else {
      const float* tp = (const float*)ta + tarow + s0 + quad * 8;
      taf0 = pack8f(tp);
      taf1 = pack8f(tp + 32);
    }
    // ---- prefetch next chunk's K-frags ----
    short8 kn[4];
    {
      int sn = s0 + 64 + scol;
      bool v = sn < len;
      const bf16* kp = h + (size_t)(rs + (v ? sn : 0)) * 128 + quad * 8;
#pragma unroll
      for (int ks = 0; ks < 4; ++ks) kn[ks] = v ? *(const short8*)(kp + ks * 32) : zero8;
    }
    // ---- QK: S[t=quad*4+r][s=scol] ----
    f32x4 sa = {0.f, 0.f, 0.f, 0.f};
#pragma unroll
    for (int ks = 0; ks < 4; ++ks)
      sa = __builtin_amdgcn_mfma_f32_16x16x32_bf16(qf[ks], kf[ks], sa, 0, 0, 0);
#pragma unroll
    for (int ks = 0; ks < 4; ++ks) kf[ks] = kn[ks];

    const bool sval = (s0 + scol) < len;
    float cm[4];
#pragma unroll
    for (int r = 0; r < 4; ++r) cm[r] = sval ? sa[r] * scale : -INFINITY;
    // intra-wave row max over the 16 lanes of each quad
#pragma unroll
    for (int off = 1; off <= 8; off <<= 1) {
#pragma unroll
      for (int r = 0; r < 4; ++r) cm[r] = fmaxf(cm[r], __shfl_xor(cm[r], off, 64));
    }
    if (m16 == 0) {
#pragma unroll
      for (int r = 0; r < 4; ++r) wmax[wv][quad * 4 + r] = cm[r];
    }
    __syncthreads();                                   // bar1: vT + wmax ready

    float mnew[4], al[4], p[4];
#pragma unroll
    for (int r = 0; r < 4; ++r) {
      int row = quad * 4 + r;
      float cmax = fmaxf(fmaxf(wmax[0][row], wmax[1][row]),
                         fmaxf(wmax[2][row], wmax[3][row]));
      float mold = mrun[row];
      mnew[r] = fmaxf(mold, cmax);                     // finite: >=1 valid col
      al[r] = __expf(mold - mnew[r]);                  // 0 on first chunk
      p[r] = sval ? __expf(sa[r] * scale - mnew[r]) : 0.f;
    }
    float cs[4];
#pragma unroll
    for (int r = 0; r < 4; ++r) cs[r] = p[r];
#pragma unroll
    for (int off = 1; off <= 8; off <<= 1) {
#pragma unroll
      for (int r = 0; r < 4; ++r) cs[r] += __shfl_xor(cs[r], off, 64);
    }
    if (m16 == 0) {
#pragma unroll
      for (int r = 0; r < 4; ++r) wsum[wv][quad * 4 + r] = cs[r];
    }
#pragma unroll
    for (int r = 0; r < 4; ++r)
      Pbuf[quad * 4 + r][wv * 16 + m16] = (unsigned short)f2bs(p[r]);
    __syncthreads();                                   // bar2: Pbuf + wsum ready

    if (wv == 0 && m16 == 0) {
#pragma unroll
      for (int r = 0; r < 4; ++r) {
        int row = quad * 4 + r;
        float st = wsum[0][row] + wsum[1][row] + wsum[2][row] + wsum[3][row];
        lrun[row] = lrun[row] * al[r] + st;
        mrun[row] = mnew[r];
      }
    }
    // rescale P-accumulator by alpha (per row); ta-acc is linear, untouched
#pragma unroll
    for (int ct = 0; ct < 2; ++ct) {
#pragma unroll
      for (int r = 0; r < 4; ++r) accp[ct][r] *= al[r];
    }
    // ---- PV + taV ----
#pragma unroll
    for (int ks = 0; ks < 2; ++ks) {
      short8 pf = *(const short8*)&Pbuf[m16][ks * 32 + quad * 8];
      short8 tf = ks ? taf1 : taf0;
#pragma unroll
      for (int ct = 0; ct < 2; ++ct) {
        const int c0 = wv * 32 + ct * 16;
        const unsigned short* vrow = &vT[c0 + m16][ks * 32 + quad * 8];
        unsigned w0 = *(const unsigned*)(vrow + 0);
        unsigned w1 = *(const unsigned*)(vrow + 2);
        unsigned w2 = *(const unsigned*)(vrow + 4);
        unsigned w3 = *(const unsigned*)(vrow + 6);
        short8 bfv;
        bfv[0] = (short)(w0 & 0xffffu); bfv[1] = (short)(w0 >> 16);
        bfv[2] = (short)(w1 & 0xffffu); bfv[3] = (short)(w1 >> 16);
        bfv[4] = (short)(w2 & 0xffffu); bfv[5] = (short)(w2 >> 16);
        bfv[6] = (short)(w3 & 0xffffu); bfv[7] = (short)(w3 >> 16);
        if (ct == 0) {
          accp[0] = __builtin_amdgcn_mfma_f32_16x16x32_bf16(pf, bfv, accp[0], 0, 0, 0);
          acct[0] = __builtin_amdgcn_mfma_f32_16x16x32_bf16(tf, bfv, acct[0], 0, 0, 0);
        } else {
          accp[1] = __builtin_amdgcn_mfma_f32_16x16x32_bf16(pf, bfv, accp[1], 0, 0, 0);
          acct[1] = __builtin_amdgcn_mfma_f32_16x16x32_bf16(tf, bfv, acct[1], 0, 0, 0);
        }
      }
    }
    __syncthreads();                                   // bar3: protect vT/Pbuf
  }

  // ---- epilogue: analytic zero-pad term, normalize, add ta part ----
#pragma unroll
  for (int r = 0; r < 4; ++r) {
    int t = quad * 4 + r;
    if (t < nrows) {
      float m_r = mrun[t], l_r = lrun[t];
      float m_f = (len < T) ? fmaxf(m_r, 0.f) : m_r;
      float corr = __expf(m_r - m_f);
      float l_f = l_r * corr + (float)(T - len) * __expf(-m_f);
      float os = corr / l_f;
      size_t ob = (size_t)(rs + t0 + t) * 128;
      st1(xout, ob + wv * 32 + m16,      isbf, accp[0][r] * os + acct[0][r]);
      st1(xout, ob + wv * 32 + 16 + m16, isbf, accp[1][r] * os + acct[1][r]);
    }
  }
}

// ---------------------------------------------------------------------------
extern "C" void kernel_launch(void* const* d_in, const int* in_sizes, int n_in,
                              void* d_out, int out_size, void* d_ws, size_t ws_size,
                              hipStream_t stream) {
  const void* x_temp    = d_in[0];
  const void* x_stat    = d_in[1];
  const void* temp_attn = d_in[2];
  const int N = in_sizes[0] / 128;      // 23450
  const int B = in_sizes[1] / 64;       // 32
  long long tt = (long long)in_sizes[2] / B;
  int T = 1; while ((long long)(T + 1) * (T + 1) <= tt) ++T;  // isqrt -> 1024

  int p = 3;
  while (p < n_in && in_sizes[p] != N) ++p;
  const int* batch_idx = (const int*)d_in[p++];
  const int* pos_idx   = (const int*)d_in[p++];
  const void* W1 = d_in[p++];
  const void* b1 = d_in[p++];
  const void* g1 = d_in[p++];
  const void* be1= d_in[p++];
  const void* mn1= d_in[p++];
  const void* vr1= d_in[p++];
  const void* W2 = d_in[p++];
  const void* b2 = d_in[p++];
  const void* g2 = d_in[p++];
  const void* be2= d_in[p++];
  const void* mn2= d_in[p++];
  const void* vr2= d_in[p++];

  int*  meta = (int*)d_ws;
  int*  rs   = meta;
  int*  lnp  = meta + B;
  int*  flag = meta + 2 * B;
  bf16* h    = (bf16*)((char*)d_ws + 1024);
  bf16* w1b  = h + (size_t)N * 128;
  const int w1n = 128 * 192;
  size_t need = 1024 + (size_t)N * 128 * sizeof(bf16) + (size_t)w1n * sizeof(bf16);

  long long obase = (long long)N * 128;

  meta_kernel<<<90, 256, 0, stream>>>(x_temp, batch_idx, pos_idx, N, B, rs, lnp,
                                      flag, W1, w1b, w1n);
  stat_kernel<<<B, 64, 0, stream>>>(x_stat, W2, b2, g2, be2, mn2, vr2, flag,
                                    d_out, obase);
  if (ws_size >= need) {
    h_mfma_kernel<<<(N + 63) / 64, 256, 0, stream>>>(x_temp, x_stat, batch_idx,
                                                     w1b, b1, g1, be1, mn1, vr1,
                                                     flag, h, N);
    attn_mfma_kernel<<<dim3((T + 15) / 16, B), 256, 0, stream>>>(
        temp_attn, h, rs, lnp, flag, d_out, T, N);
  } else {
    zfill_kernel<<<512, 256, 0, stream>>>(d_out, flag, obase);
  }
}